// Round 7
// baseline (3585.459 us; speedup 1.0000x reference)
//
#include <hip/hip_runtime.h>
#include <math.h>

// LSTM: B=64, T=2048, I=200, H=100. Output h_T [64,100] fp32.
// R7: input projection FUSED into the recurrence kernel (xproj/xg round-trip deleted).
//   prep_w : W_hh -> bf16 A-frags (M=512,K=128), W_ih -> bf16 A-frags (M=512,K=224),
//            biasq[4q+r] = b_ih+b_hh in unit-quad order. Gate permute g' = 4q+s.
//   prep_xB: x -> bf16 B-frag layout [b][t][kt(7)][32], zero-padded K 200->224.
//   lstm   : 64 WGs (one per batch), 256 thr = 4 waves, 1 wave/SIMD.
//            Per step: 32 MFMA (h matvec, dots->glds) | bar | upd lanes (25/wave)
//            activations from glds + xglds ring + biasq | 56 MFMA (xg(t+1) -> xglds
//            ring, independent of h => fills the stall shadow) | bar.
//            W_hh+W_ih frags resident (352 regs, AGPR-eligible: MFMA-only use).

#define T_TOTAL 2048
#define B_SZ 64
#define IN_SZ 200
#define H_SZ 100
#define KXP 224
#define NKT 7

typedef __attribute__((ext_vector_type(8))) short s8v;   // 8 bf16
typedef __attribute__((ext_vector_type(4))) float f4v;   // MFMA C/D frag

__device__ __forceinline__ float sigf(float x) {
    return __builtin_amdgcn_rcpf(1.f + __expf(-x));
}
__device__ __forceinline__ short bf16_rne(float f) {
    unsigned u = __float_as_uint(f);
    u += 0x7FFF + ((u >> 16) & 1);
    return (short)(u >> 16);
}
__device__ __forceinline__ void lds_barrier() {
    asm volatile("s_waitcnt lgkmcnt(0)\n\ts_barrier" ::: "memory");
}

// ---------------- prep: weights -> MFMA A-frags + bias quads ----------------
__global__ void prep_w(const float* __restrict__ W_ih, const float* __restrict__ W_hh,
                       const float* __restrict__ b_ih, const float* __restrict__ b_hh,
                       short* __restrict__ WAh, short* __restrict__ WAx,
                       float* __restrict__ biasq) {
    int e = blockIdx.x * 256 + threadIdx.x;
    if (e < 512 * 128) {  // WAh: (((w*8+mt)*4+kt)*64+lane)*8+j
        int j = e & 7, lane = (e >> 3) & 63, kt = (e >> 9) & 3, mt = (e >> 11) & 7, w = e >> 14;
        int gp = 128 * w + 16 * mt + (lane & 15);
        int k = kt * 32 + ((lane >> 4) << 3) + j;
        float v = 0.f;
        if (gp < 400 && k < H_SZ) v = W_hh[((gp & 3) * H_SZ + (gp >> 2)) * H_SZ + k];
        WAh[e] = bf16_rne(v);
    }
    if (e < 512 * KXP) {  // WAx: (((w*8+mt)*7+kt)*64+lane)*8+j
        int j = e & 7, lane = (e >> 3) & 63, r = e >> 9;
        int kt = r % NKT, mtw = r / NKT, mt = mtw & 7, w = mtw >> 3;
        int gp = 128 * w + 16 * mt + (lane & 15);
        int k = kt * 32 + ((lane >> 4) << 3) + j;
        float v = 0.f;
        if (gp < 400 && k < IN_SZ) v = W_ih[((gp & 3) * H_SZ + (gp >> 2)) * IN_SZ + k];
        WAx[e] = bf16_rne(v);
    }
    if (e < 512) {  // biasq[4q+r]
        int q = e >> 2, r = e & 3;
        biasq[e] = (q < H_SZ) ? (b_ih[r * H_SZ + q] + b_hh[r * H_SZ + q]) : 0.f;
    }
}

// ---------------- prep: x -> bf16 B-frag stream, chunk [t0, t0+Tlen) ----------------
// xB[((b*Tlen+tl)*7+kt)*32 + m] = bf16(x[b][t0+tl][kt*32+m]) or 0 beyond K=200
__global__ void prep_xB(const float* __restrict__ x, short* __restrict__ xB,
                        int t0, int Tlen) {
    int e = blockIdx.x * 256 + threadIdx.x;
    if (e >= B_SZ * Tlen * KXP) return;
    int m = e & 31;
    int r = e >> 5;
    int kt = r % NKT;
    int bt = r / NKT;                   // b*Tlen + tl
    int b = bt / Tlen, tl = bt - b * Tlen;
    int k = kt * 32 + m;
    float v = (k < IN_SZ) ? x[((size_t)(b * T_TOTAL + t0 + tl)) * IN_SZ + k] : 0.f;
    xB[e] = bf16_rne(v);
}

// ---------------- fused recurrence ----------------
__global__ __attribute__((amdgpu_flat_work_group_size(256, 256), amdgpu_waves_per_eu(1, 1)))
void lstm_kernel(const short* __restrict__ xB, const short* __restrict__ WAh,
                 const short* __restrict__ WAx, const float* __restrict__ biasq,
                 float* __restrict__ hstate, float* __restrict__ cstate,
                 float* __restrict__ out, int Tlen, int first, int last) {
    __shared__ __align__(16) short hlds[128];       // bf16 h
    __shared__ __align__(16) float glds[512];       // h-matvec dots (g' order)
    __shared__ __align__(16) float xglds[2][512];   // xg ring (g' order)

    const int b = blockIdx.x;
    const int tid = threadIdx.x;
    const int w = tid >> 6, l = tid & 63, u = l >> 4;
    const bool blx = ((l & 15) == 0);     // col-0 lanes: D extraction
    const bool upd = (l < 25);
    const int uq = 25 * w + l;            // this lane's hidden unit (if upd)

    // resident A-fragments: h-side 128 regs, x-side 224 regs (MFMA-only use -> AGPR)
    s8v afh[8][4], afx[8][7];
    {
        const s8v* A = (const s8v*)WAh;
#pragma unroll
        for (int mt = 0; mt < 8; ++mt)
#pragma unroll
            for (int kt = 0; kt < 4; ++kt)
                afh[mt][kt] = A[((w * 8 + mt) * 4 + kt) * 64 + l];
    }
    {
        const s8v* A = (const s8v*)WAx;
#pragma unroll
        for (int mt = 0; mt < 8; ++mt)
#pragma unroll
            for (int kt = 0; kt < NKT; ++kt)
                afx[mt][kt] = A[((w * 8 + mt) * NKT + kt) * 64 + l];
    }

    float c = 0.f, hval = 0.f;
    f4v bq; bq[0] = bq[1] = bq[2] = bq[3] = 0.f;
    if (upd) {
        bq = ((const f4v*)biasq)[uq];
        c = first ? 0.f : cstate[b * H_SZ + uq];
    }
    if (tid < 128) hlds[tid] = (tid < H_SZ && !first) ? bf16_rne(hstate[b * H_SZ + tid]) : (short)0;

    const s8v* xb8 = (const s8v*)xB;
    const size_t xbase = (size_t)b * Tlen * (NKT * 4) + u;  // s8v units; +4*(tl*7+kt)

    // prologue: xg(0) -> xglds[0]; preload B-frags for xg(1)
    s8v bxc[NKT], bxn[NKT];
    {
        s8v bx0[NKT];
        int t1 = (Tlen > 1) ? 1 : 0;
#pragma unroll
        for (int kt = 0; kt < NKT; ++kt) bx0[kt] = xb8[xbase + (size_t)(0 * NKT + kt) * 4];
#pragma unroll
        for (int kt = 0; kt < NKT; ++kt) bxc[kt] = xb8[xbase + (size_t)(t1 * NKT + kt) * 4];
#pragma unroll
        for (int mt = 0; mt < 8; ++mt) {
            f4v a; a[0] = a[1] = a[2] = a[3] = 0.f;
#pragma unroll
            for (int kt = 0; kt < NKT; ++kt)
                a = __builtin_amdgcn_mfma_f32_16x16x32_bf16(afx[mt][kt], bx0[kt], a, 0, 0, 0);
            if (blx) *(f4v*)&xglds[0][w * 128 + mt * 16 + u * 4] = a;
        }
    }
    __syncthreads();  // one-time full barrier (hlds init + xglds[0])

    for (int t = 0; t < Tlen; ++t) {
        // issue loads for xg(t+2) B-frags (consumed next iteration)
        int t2 = t + 2; if (t2 > Tlen - 1) t2 = Tlen - 1;
#pragma unroll
        for (int kt = 0; kt < NKT; ++kt)
            bxn[kt] = xb8[xbase + ((size_t)t2 * NKT + kt) * 4];

        // h matvec: dots -> glds
        s8v bh[4];
#pragma unroll
        for (int kt = 0; kt < 4; ++kt)
            bh[kt] = *(const s8v*)&hlds[kt * 32 + u * 8];
#pragma unroll
        for (int mt = 0; mt < 8; ++mt) {
            f4v a; a[0] = a[1] = a[2] = a[3] = 0.f;
#pragma unroll
            for (int kt = 0; kt < 4; ++kt)
                a = __builtin_amdgcn_mfma_f32_16x16x32_bf16(afh[mt][kt], bh[kt], a, 0, 0, 0);
            if (blx) *(f4v*)&glds[w * 128 + mt * 16 + u * 4] = a;
        }
        lds_barrier();  // bar1: dots visible

        // gate update (25 lanes/wave), interleaves with x-matvec below
        if (upd) {
            f4v gd = *(const f4v*)&glds[4 * uq];
            f4v xa = *(const f4v*)&xglds[t & 1][4 * uq];
            float gi = gd[0] + xa[0] + bq[0];
            float gf = gd[1] + xa[1] + bq[1];
            float gg = gd[2] + xa[2] + bq[2];
            float go = gd[3] + xa[3] + bq[3];
            float iv = sigf(gi);
            float fv = sigf(gf);
            float gv = __builtin_fmaf(sigf(2.f * gg), 2.f, -1.f);  // tanh
            float ov = sigf(go);
            c = __builtin_fmaf(fv, c, iv * gv);
            float tc = __builtin_fmaf(sigf(2.f * c), 2.f, -1.f);   // tanh(c)
            hval = ov * tc;
            hlds[uq] = bf16_rne(hval);
        }

        // x matvec for xg(t+1) -> ring (independent of h; fills the shadow)
        {
            int dst = (t + 1) & 1;
#pragma unroll
            for (int mt = 0; mt < 8; ++mt) {
                f4v a; a[0] = a[1] = a[2] = a[3] = 0.f;
#pragma unroll
                for (int kt = 0; kt < NKT; ++kt)
                    a = __builtin_amdgcn_mfma_f32_16x16x32_bf16(afx[mt][kt], bxc[kt], a, 0, 0, 0);
                if (blx) *(f4v*)&xglds[dst][w * 128 + mt * 16 + u * 4] = a;
            }
        }
#pragma unroll
        for (int kt = 0; kt < NKT; ++kt) bxc[kt] = bxn[kt];
        lds_barrier();  // bar2: h + xg(t+1) visible
    }

    if (upd) {
        hstate[b * H_SZ + uq] = hval;
        cstate[b * H_SZ + uq] = c;
        if (last) out[b * H_SZ + uq] = hval;
    }
}

// ---------------- host ----------------
extern "C" void kernel_launch(void* const* d_in, const int* in_sizes, int n_in,
                              void* d_out, int out_size, void* d_ws, size_t ws_size,
                              hipStream_t stream) {
    const float* x    = (const float*)d_in[0];
    const float* W_ih = (const float*)d_in[1];
    const float* W_hh = (const float*)d_in[2];
    const float* b_ih = (const float*)d_in[3];
    const float* b_hh = (const float*)d_in[4];
    float* out = (float*)d_out;

    char* ws = (char*)d_ws;
    short* WAh   = (short*)(ws);              // 131072 B
    short* WAx   = (short*)(ws + 131072);     // 229376 B
    float* biasq = (float*)(ws + 360448);     // 2048 B
    float* hstate = (float*)(ws + 362496);    // 25600 B
    float* cstate = (float*)(ws + 388096);    // 25600 B
    short* xB    = (short*)(ws + 413696);     // chunk: Tc*64*224*2 B

    size_t cap = (ws_size > 413696) ? (ws_size - 413696) : 0;
    long long tcmax = (long long)(cap / ((size_t)B_SZ * KXP * 2));
    int Tc = (int)tcmax;
    if (Tc > T_TOTAL) Tc = T_TOTAL;
    if (Tc < 1) Tc = 1;
    // prefer equal chunks
    int nchunk = (T_TOTAL + Tc - 1) / Tc;
    Tc = (T_TOTAL + nchunk - 1) / nchunk;

    prep_w<<<448, 256, 0, stream>>>(W_ih, W_hh, b_ih, b_hh, WAh, WAx, biasq);

    for (int t0 = 0; t0 < T_TOTAL; t0 += Tc) {
        int Tlen = T_TOTAL - t0;
        if (Tlen > Tc) Tlen = Tc;
        int nel = B_SZ * Tlen * KXP;
        prep_xB<<<(nel + 255) / 256, 256, 0, stream>>>(x, xB, t0, Tlen);
        lstm_kernel<<<B_SZ, 256, 0, stream>>>(xB, WAh, WAx, biasq, hstate, cstate, out,
                                              Tlen, t0 == 0 ? 1 : 0,
                                              (t0 + Tlen) == T_TOTAL ? 1 : 0);
    }
}

// Round 8
// 1825.890 us; speedup vs baseline: 1.9637x; 1.9637x over previous
//
#include <hip/hip_runtime.h>
#include <math.h>

// LSTM: B=64, T=2048, I=200, H=100. Output h_T [64,100] fp32.
// R8: lstm_kernel = R6 exactly (proven 1470us, absmax 2e-3).
//     xproj = bf16 MFMA GEMM (R7-proven numerics), fp32 xg out in unit-quad order,
//     bias folded into accumulator init. A-frags re-read from L2 per tile (NOT
//     resident - R7 showed 352 resident frag regs spill and cost 2.3x).
//   prep_w : W_hh -> bf16 A-frags (M=512,K=128); W_ih -> bf16 A-frags (M=512,K=224);
//            biasq[4q+r] = b_ih+b_hh in unit-quad order. Gate permute g' = 4q+s.
//   xproj  : per WG: 64 t x 512 g'. x slab fp32 -> LDS -> bf16 B-frags;
//            56 MFMA per wave per 16-t block; D -> LDS slab -> coalesced fp32 stores.
//   lstm   : 64 WGs, 256 thr, W_hh A-frags resident (128 regs), 32 MFMA/step,
//            lds_barrier (lgkmcnt-only) x2 per step.

#define T_TOTAL 2048
#define B_SZ 64
#define IN_SZ 200
#define H_SZ 100
#define GP 512
#define KXP 224
#define NKT 7

typedef __attribute__((ext_vector_type(8))) short s8v;   // 8 bf16
typedef __attribute__((ext_vector_type(4))) float f4v;   // MFMA C/D frag

__device__ __forceinline__ float sigf(float x) {
    return __builtin_amdgcn_rcpf(1.f + __expf(-x));
}
__device__ __forceinline__ short bf16_rne(float f) {
    unsigned u = __float_as_uint(f);
    u += 0x7FFF + ((u >> 16) & 1);
    return (short)(u >> 16);
}
__device__ __forceinline__ void lds_barrier() {
    asm volatile("s_waitcnt lgkmcnt(0)\n\ts_barrier" ::: "memory");
}

// ---------------- prep: weights -> MFMA A-frags + bias quads ----------------
__global__ void prep_w(const float* __restrict__ W_ih, const float* __restrict__ W_hh,
                       const float* __restrict__ b_ih, const float* __restrict__ b_hh,
                       short* __restrict__ WAh, short* __restrict__ WAx,
                       float* __restrict__ biasq) {
    int e = blockIdx.x * 256 + threadIdx.x;
    if (e < 512 * 128) {  // WAh: (((w*8+mt)*4+kt)*64+lane)*8+j
        int j = e & 7, lane = (e >> 3) & 63, kt = (e >> 9) & 3, mt = (e >> 11) & 7, w = e >> 14;
        int gp = 128 * w + 16 * mt + (lane & 15);
        int k = kt * 32 + ((lane >> 4) << 3) + j;
        float v = 0.f;
        if (gp < 400 && k < H_SZ) v = W_hh[((gp & 3) * H_SZ + (gp >> 2)) * H_SZ + k];
        WAh[e] = bf16_rne(v);
    }
    if (e < 512 * KXP) {  // WAx: (((w*8+mt)*7+kt)*64+lane)*8+j
        int j = e & 7, lane = (e >> 3) & 63, r = e >> 9;
        int kt = r % NKT, mtw = r / NKT, mt = mtw & 7, w = mtw >> 3;
        int gp = 128 * w + 16 * mt + (lane & 15);
        int k = kt * 32 + ((lane >> 4) << 3) + j;
        float v = 0.f;
        if (gp < 400 && k < IN_SZ) v = W_ih[((gp & 3) * H_SZ + (gp >> 2)) * IN_SZ + k];
        WAx[e] = bf16_rne(v);
    }
    if (e < 512) {  // biasq[4q+r]
        int q = e >> 2, r = e & 3;
        biasq[e] = (q < H_SZ) ? (b_ih[r * H_SZ + q] + b_hh[r * H_SZ + q]) : 0.f;
    }
}

// ---------------- input projection: bf16 MFMA GEMM ----------------
// Grid (Tlen/64, B). WG: 256 thr / 4 waves; wave w owns g' rows w*128..+127.
// For each of 4 16-t blocks: stage x fp32 -> LDS; build bf16 B-frags; 8mt x 7kt MFMA
// (acc init = biasq); D -> padded LDS slab; coalesced fp32 stores to xg quad layout.
__global__ __launch_bounds__(256, 2) void xproj_kernel(
    const float* __restrict__ x, const short* __restrict__ WAx,
    const float* __restrict__ biasq, float* __restrict__ xg,
    int t0, int Tlen) {
    __shared__ __align__(16) float xst[16][228];   // x slab (fp32), k 200..227 stay 0
    __shared__ __align__(16) float slab[16][516];  // D slab [t][g'] padded

    const int tid = threadIdx.x;
    const int w = tid >> 6, l = tid & 63;
    const int u = l >> 4, col = l & 15;
    const int slabt = blockIdx.x;      // 64-t slab within chunk
    const int b = blockIdx.y;
    const int tg0 = t0 + slabt * 64;   // global t of slab start

    // zero the k-padding once (never rewritten)
    for (int idx = tid; idx < 16 * 28; idx += 256) {
        xst[idx / 28][200 + idx % 28] = 0.f;
    }
    __syncthreads();

    const f4v* x4 = (const f4v*)x;       // x row = 50 f4v
    const s8v* A8 = (const s8v*)WAx;
    const f4v* bq4 = (const f4v*)biasq;
    f4v* xg4 = (f4v*)xg;

    for (int nb = 0; nb < 4; ++nb) {
        // stage 16 t-rows of x (fp32, coalesced)
        for (int idx = tid; idx < 16 * 50; idx += 256) {
            int r = idx / 50, c4 = idx % 50;
            f4v v = x4[(size_t)(b * T_TOTAL + tg0 + nb * 16 + r) * 50 + c4];
            *(f4v*)&xst[r][c4 * 4] = v;
        }
        __syncthreads();

        // B-frags: lane provides B[k=kt*32+u*8+j][n=col] = bf16(x[t=col][k])
        s8v bx[NKT];
#pragma unroll
        for (int kt = 0; kt < NKT; ++kt) {
            const float* src = &xst[col][kt * 32 + u * 8];
            f4v lo = *(const f4v*)src;
            f4v hi = *(const f4v*)(src + 4);
            s8v f;
            f[0] = bf16_rne(lo[0]); f[1] = bf16_rne(lo[1]);
            f[2] = bf16_rne(lo[2]); f[3] = bf16_rne(lo[3]);
            f[4] = bf16_rne(hi[0]); f[5] = bf16_rne(hi[1]);
            f[6] = bf16_rne(hi[2]); f[7] = bf16_rne(hi[3]);
            bx[kt] = f;
        }

#pragma unroll
        for (int mt = 0; mt < 8; ++mt) {
            f4v acc = bq4[32 * w + 4 * mt + u];   // bias init (per-row, all cols)
#pragma unroll
            for (int kt = 0; kt < NKT; ++kt)
                acc = __builtin_amdgcn_mfma_f32_16x16x32_bf16(
                    A8[((w * 8 + mt) * NKT + kt) * 64 + l], bx[kt], acc, 0, 0, 0);
            // D: row = w*128+mt*16+u*4+reg (g'), col = t
            *(f4v*)&slab[col][w * 128 + mt * 16 + u * 4] = acc;
        }
        __syncthreads();

        // coalesced stores: xg[(b*Tlen + tloc)*128 + c4] (f4v units)
        for (int idx = tid; idx < 16 * 128; idx += 256) {
            int t = idx >> 7, c4 = idx & 127;
            f4v v = *(const f4v*)&slab[t][c4 * 4];
            xg4[(size_t)(b * Tlen + slabt * 64 + nb * 16 + t) * 128 + c4] = v;
        }
        __syncthreads();
    }
}

// ---------------- recurrence: MFMA matvec, one WG (256 thr) per batch (R6 exact) ----------------
__global__ __attribute__((amdgpu_flat_work_group_size(256, 256), amdgpu_waves_per_eu(1, 1)))
void lstm_kernel(
    const float* __restrict__ xg, const short* __restrict__ WA,
    float* __restrict__ hstate, float* __restrict__ cstate,
    float* __restrict__ out, int Tlen, int first, int last) {
    __shared__ __align__(16) short hlds[128];   // bf16 h, [100..127] stay 0
    __shared__ __align__(16) float glds[512];   // gate dots, permuted g' order

    const int b = blockIdx.x;
    const int tid = threadIdx.x;
    const int w = tid >> 6;
    const int l = tid & 63;

    // A-fragments: 8 M-tiles x 4 K-tiles (128 regs, MFMA-only use)
    s8v afr[8][4];
    {
        const s8v* WA8 = (const s8v*)WA;
#pragma unroll
        for (int mt = 0; mt < 8; ++mt)
#pragma unroll
            for (int kt = 0; kt < 4; ++kt)
                afr[mt][kt] = WA8[((w * 8 + mt) * 4 + kt) * 64 + l];
    }

    const bool upd = (tid < H_SZ);
    float c = 0.f;
    float hval = 0.f;
    if (upd) c = first ? 0.f : cstate[b * H_SZ + tid];
    if (tid < 128) hlds[tid] = (upd && !first) ? bf16_rne(hstate[b * H_SZ + tid]) : (short)0;
    __syncthreads();  // one-time full barrier (init)

    const f4v* xg4 = (const f4v*)xg;
    const size_t xbase = (size_t)b * Tlen * (GP / 4);
    f4v xa, xb;
#pragma unroll
    for (int i = 0; i < 4; ++i) { xa[i] = 0.f; xb[i] = 0.f; }
    if (upd) {
        xa = xg4[xbase + tid];
        xb = xg4[xbase + (size_t)((Tlen > 1) ? 1 : 0) * (GP / 4) + tid];
    }

    const bool bl = ((l & 15) == 0);      // col-0 lanes: B-frag source + D extraction
    const int krow = (l >> 4) << 3;       // 0,8,16,24
    s8v zf;
#pragma unroll
    for (int i = 0; i < 8; ++i) zf[i] = 0;

    for (int tl = 0; tl < Tlen; ++tl) {
        int tpre = tl + 2; if (tpre >= Tlen) tpre = Tlen - 1;
        f4v xn = xb;
        if (upd) xn = xg4[xbase + (size_t)tpre * (GP / 4) + tid];  // stays in flight

        // B-fragments: column 0 = h (bf16), rest zero
        s8v bfr[4];
#pragma unroll
        for (int kt = 0; kt < 4; ++kt)
            bfr[kt] = bl ? *(const s8v*)&hlds[kt * 32 + krow] : zf;

        // 8 M-tiles x 4 K accumulations
        f4v acc[8];
#pragma unroll
        for (int mt = 0; mt < 8; ++mt) {
#pragma unroll
            for (int i = 0; i < 4; ++i) acc[mt][i] = 0.f;
#pragma unroll
            for (int kt = 0; kt < 4; ++kt)
                acc[mt] = __builtin_amdgcn_mfma_f32_16x16x32_bf16(afr[mt][kt], bfr[kt], acc[mt], 0, 0, 0);
        }

        // extract col 0: lane 16u holds rows (4u..4u+3) of each tile
        if (bl) {
            int rbase = w * 128 + ((l >> 4) << 2);
#pragma unroll
            for (int mt = 0; mt < 8; ++mt)
                *(f4v*)&glds[rbase + mt * 16] = acc[mt];
        }
        lds_barrier();

        if (upd) {
            f4v gd = *(const f4v*)&glds[4 * tid];
            float gi = gd[0] + xa[0];
            float gf = gd[1] + xa[1];
            float gg = gd[2] + xa[2];
            float go = gd[3] + xa[3];
            float iv = sigf(gi);
            float fv = sigf(gf);
            float gv = __builtin_fmaf(sigf(2.f * gg), 2.f, -1.f);  // tanh
            float ov = sigf(go);
            c = __builtin_fmaf(fv, c, iv * gv);
            float tc = __builtin_fmaf(sigf(2.f * c), 2.f, -1.f);   // tanh(c)
            hval = ov * tc;
            hlds[tid] = bf16_rne(hval);
        }
        lds_barrier();
        xa = xb; xb = xn;
    }

    if (upd) {
        hstate[b * H_SZ + tid] = hval;
        cstate[b * H_SZ + tid] = c;
        if (last) out[b * H_SZ + tid] = hval;
    }
}

// ---------------- host ----------------
extern "C" void kernel_launch(void* const* d_in, const int* in_sizes, int n_in,
                              void* d_out, int out_size, void* d_ws, size_t ws_size,
                              hipStream_t stream) {
    const float* x    = (const float*)d_in[0];
    const float* W_ih = (const float*)d_in[1];
    const float* W_hh = (const float*)d_in[2];
    const float* b_ih = (const float*)d_in[3];
    const float* b_hh = (const float*)d_in[4];
    float* out = (float*)d_out;

    char* ws = (char*)d_ws;
    short* WAh    = (short*)(ws);             // 131072 B
    short* WAx    = (short*)(ws + 131072);    // 229376 B
    float* biasq  = (float*)(ws + 360448);    // 2048 B
    float* hstate = (float*)(ws + 362496);    // 25600 B
    float* cstate = (float*)(ws + 388096);    // 25600 B
    float* xgbuf  = (float*)(ws + 413696);    // chunk: Tc*64*512*4 B

    size_t cap = (ws_size > 413696) ? (ws_size - 413696) : 0;
    long long tcmax = (long long)(cap / ((size_t)B_SZ * GP * 4));
    int Tc = (int)((tcmax / 64) * 64);
    if (Tc > T_TOTAL) Tc = T_TOTAL;
    if (Tc < 64) Tc = 64;

    prep_w<<<448, 256, 0, stream>>>(W_ih, W_hh, b_ih, b_hh, WAh, WAx, biasq);

    for (int t0 = 0; t0 < T_TOTAL; t0 += Tc) {
        int Tlen = T_TOTAL - t0;
        if (Tlen > Tc) Tlen = Tc;
        xproj_kernel<<<dim3(Tlen / 64, B_SZ), 256, 0, stream>>>(x, WAx, biasq, xgbuf, t0, Tlen);
        lstm_kernel<<<B_SZ, 256, 0, stream>>>(xgbuf, WAh, hstate, cstate, out,
                                              Tlen, t0 == 0 ? 1 : 0,
                                              (t0 + Tlen) == T_TOTAL ? 1 : 0);
    }
}